// Round 4
// baseline (577.597 us; speedup 1.0000x reference)
//
#include <hip/hip_runtime.h>

// LogicConv3d: B=4, C=3, H=W=D=32, K=32, S=16 leaves, tree depth 4 (31 LUT nodes).
// Out: (B, K, 30, 30, 30) = 3,456,000 fp32.
//
// R3: block = (b,k,oh). Stage the oh-slab of x (3c x 3h x 32w x 32d, padded
// w-stride 36 -> 41.5KB) into LDS with coalesced float4 loads; gathers become
// ds_read_b32. Process 4 positions/thread level-by-level (SoA) so each node's
// 4 LUT constants are one ds_read_b128 amortized over 4 positions. Eval in
// float2 pairs to get v_pk_fma_f32. Leaf bases scalarized via readfirstlane.

#define B_  4
#define C_  3
#define H_  32
#define W_  32
#define D_  32
#define K_  32
#define S_  16
#define P_  900     // positions per oh-row (30*30)
#define WS  36      // padded w-stride in slab (dwords); 36*4=144B, 16B-aligned rows
#define TPB 256

typedef float v2f __attribute__((ext_vector_type(2)));

__global__ __launch_bounds__(TPB, 3) void logic_conv3d(
    const float* __restrict__ x,
    const int*   __restrict__ kc,
    const float* __restrict__ w0,
    const float* __restrict__ w1,
    const float* __restrict__ w2,
    const float* __restrict__ w3,
    const float* __restrict__ w4,
    float*       __restrict__ out)
{
    __shared__ float4 s_lut[31];                       // (l0, d1, d2, d3) per node
    __shared__ int    s_lb[32];                        // leaf base in slab coords
    __shared__ __align__(16) float slab[3 * 3 * 32 * WS];  // 10368 floats = 41.5KB

    const int oh  = blockIdx.x;      // 0..29
    const int bk  = blockIdx.y;      // b*K + k
    const int b   = bk >> 5;
    const int k   = bk & 31;
    const int tid = threadIdx.x;

    // ---- per-block setup: 31 softmax->LUT (delta form) + 32 slab-coord bases ----
    if (tid < 31) {
        const float* wp; int ln;
        if      (tid < 16) { wp = w0; ln = tid;      }
        else if (tid < 24) { wp = w1; ln = tid - 16; }
        else if (tid < 28) { wp = w2; ln = tid - 24; }
        else if (tid < 30) { wp = w3; ln = tid - 28; }
        else               { wp = w4; ln = 0;        }
        const float* wrow = wp + (ln * K_ + k) * 16;
        float lg[16];
        float m = -1e30f;
        #pragma unroll
        for (int g = 0; g < 16; ++g) { lg[g] = wrow[g]; m = fmaxf(m, lg[g]); }
        float z = 0.f;
        #pragma unroll
        for (int g = 0; g < 16; ++g) { lg[g] = __expf(lg[g] - m); z += lg[g]; }
        const float inv = 1.0f / z;
        float l0 = 0.f, l1 = 0.f, l2 = 0.f, l3 = 0.f;
        #pragma unroll
        for (int g = 0; g < 16; ++g) {
            float p = lg[g] * inv;           // GATES[g,t] = (g>>t)&1, t = 2*a+b
            if (g & 1) l0 += p;
            if (g & 2) l1 += p;
            if (g & 4) l2 += p;
            if (g & 8) l3 += p;
        }
        s_lut[tid] = make_float4(l0, l1 - l0, l2 - l0, (l3 - l2) - (l1 - l0));
    } else if (tid >= 32 && tid < 64) {
        const int idx  = tid - 32;           // tree*16 + s
        const int tree = idx >> 4;
        const int s    = idx & 15;
        const int off  = ((tree * K_ + k) * S_ + s) * 4;  // kc (2,K,S,4) = (h,w,d,c)
        const int h = kc[off + 0], w = kc[off + 1], d = kc[off + 2], c = kc[off + 3];
        s_lb[idx] = ((c * 3 + h) * 32 + w) * WS + d;      // slab coords
    }

    // ---- stage slab: 9 planes of 32x32 floats, fully coalesced float4 ----
    const float* xb = x + (size_t)b * (C_ * H_ * W_ * D_);
    #pragma unroll
    for (int it = 0; it < 9; ++it) {
        const int c  = it / 3;
        const int dh = it - 3 * c;
        const float4 val = *(const float4*)(xb + c * (H_ * W_ * D_) + (oh + dh) * (W_ * D_) + tid * 4);
        const int w  = tid >> 3;
        const int d4 = (tid & 7) << 2;
        *(float4*)&slab[(it * 32 + w) * WS + d4] = val;
    }
    __syncthreads();

    // scalarize leaf bases (block-uniform -> SGPRs)
    int lb[32];
    #pragma unroll
    for (int s = 0; s < 32; ++s) lb[s] = __builtin_amdgcn_readfirstlane(s_lb[s]);

    // ---- 4 positions per thread, SoA level-order ----
    int poff[4]; bool act[4];
    #pragma unroll
    for (int pi = 0; pi < 4; ++pi) {
        const int p  = pi * TPB + tid;
        act[pi] = (p < P_);
        const int pc = act[pi] ? p : (P_ - 1);
        const int ow = pc / 30;
        const int od = pc - ow * 30;
        poff[pi] = ow * WS + od;
    }

    v2f v[16][2];
    #pragma unroll
    for (int s = 0; s < 16; ++s) {
        const float4 L = s_lut[s];
        const int la = lb[s], lbb = lb[16 + s];
        v2f A01, A23, B01, B23;
        A01.x = slab[la  + poff[0]]; A01.y = slab[la  + poff[1]];
        A23.x = slab[la  + poff[2]]; A23.y = slab[la  + poff[3]];
        B01.x = slab[lbb + poff[0]]; B01.y = slab[lbb + poff[1]];
        B23.x = slab[lbb + poff[2]]; B23.y = slab[lbb + poff[3]];
        const v2f l0 = {L.x, L.x}, d1 = {L.y, L.y}, d2 = {L.z, L.z}, d3 = {L.w, L.w};
        v2f t0 = A01 * d2 + l0; t0 = B01 * d1 + t0; v[s][0] = (A01 * B01) * d3 + t0;
        v2f t1 = A23 * d2 + l0; t1 = B23 * d1 + t1; v[s][1] = (A23 * B23) * d3 + t1;
    }

    #pragma unroll
    for (int lvl = 0; lvl < 4; ++lvl) {
        const int width = 8 >> lvl;              // 8,4,2,1
        const int nbase = (lvl == 0) ? 16 : (lvl == 1) ? 24 : (lvl == 2) ? 28 : 30;
        #pragma unroll
        for (int j = 0; j < width; ++j) {
            const float4 L = s_lut[nbase + j];
            const v2f l0 = {L.x, L.x}, d1 = {L.y, L.y}, d2 = {L.z, L.z}, d3 = {L.w, L.w};
            #pragma unroll
            for (int h = 0; h < 2; ++h) {
                const v2f a = v[2 * j][h], bb = v[2 * j + 1][h];
                v2f t = a * d2 + l0; t = bb * d1 + t;
                v[j][h] = (a * bb) * d3 + t;
            }
        }
    }

    float* outp = out + (size_t)bk * (30 * P_) + oh * P_;
    const float r[4] = {v[0][0].x, v[0][0].y, v[0][1].x, v[0][1].y};
    #pragma unroll
    for (int pi = 0; pi < 4; ++pi)
        if (act[pi]) outp[pi * TPB + tid] = r[pi];
}

extern "C" void kernel_launch(void* const* d_in, const int* in_sizes, int n_in,
                              void* d_out, int out_size, void* d_ws, size_t ws_size,
                              hipStream_t stream) {
    const float* x  = (const float*)d_in[0];
    const int*   kc = (const int*)d_in[1];
    const float* w0 = (const float*)d_in[2];
    const float* w1 = (const float*)d_in[3];
    const float* w2 = (const float*)d_in[4];
    const float* w3 = (const float*)d_in[5];
    const float* w4 = (const float*)d_in[6];
    float* out = (float*)d_out;

    dim3 grid(30, B_ * K_);  // (oh, b*K+k) = 3840 blocks
    logic_conv3d<<<grid, TPB, 0, stream>>>(x, kc, w0, w1, w2, w3, w4, out);
}

// Round 5
// 96.241 us; speedup vs baseline: 6.0016x; 6.0016x over previous
//
#include <hip/hip_runtime.h>

// LogicConv3d: B=4, C=3, H=W=D=32, K=32, S=16 leaves, tree depth 4 (31 LUT nodes).
// Out: (B, K, 30, 30, 30) = 3,456,000 fp32.
//
// R4: back to global gathers (R3's LDS slab spilled ~1.3KB/thread to scratch ->
// 2GB of HBM traffic). Block = (bk, oh); leaf bases in SGPRs (readfirstlane) so
// a gather is v_add + global_load off an SGPR base. 4 positions/thread as two
// v2f pairs -> packed fp32 math, LUT constants read once per node per 4
// positions (wave-uniform ds_read_b128, conflict-free). Loads consumed per-leaf
// to keep live state ~110 VGPRs (launch_bounds(256,4) caps at 128, no spill).

#define B_  4
#define C_  3
#define H_  32
#define W_  32
#define D_  32
#define K_  32
#define S_  16
#define TPB 256

typedef float v2f __attribute__((ext_vector_type(2)));

__device__ __forceinline__ v2f lut2(v2f a, v2f b, float l0, float d1, float d2, float d3) {
    // E = l0 + a*d2 + b*d1 + (a*b)*d3   (4 packed ops for 2 positions)
    v2f t = a * d2 + l0;
    t = b * d1 + t;
    t = (a * b) * d3 + t;
    return t;
}

__global__ __launch_bounds__(TPB, 4) void logic_conv3d(
    const float* __restrict__ x,
    const int*   __restrict__ kc,
    const float* __restrict__ w0,
    const float* __restrict__ w1,
    const float* __restrict__ w2,
    const float* __restrict__ w3,
    const float* __restrict__ w4,
    float*       __restrict__ out)
{
    __shared__ float s_lut[31][4];   // (l0, d1, d2, d3) per node
    __shared__ int   s_lb[32];       // leaf dword base in flattened (C,H,W,D), oh-independent

    const int bk  = blockIdx.x;      // b*K + k
    const int oh  = blockIdx.y;      // 0..29
    const int b   = bk >> 5;
    const int k   = bk & 31;
    const int tid = threadIdx.x;

    // ---- per-block setup: 31 softmax->LUT (delta form) + 32 leaf bases ----
    if (tid < 31) {
        const float* wp; int ln;
        if      (tid < 16) { wp = w0; ln = tid;      }
        else if (tid < 24) { wp = w1; ln = tid - 16; }
        else if (tid < 28) { wp = w2; ln = tid - 24; }
        else if (tid < 30) { wp = w3; ln = tid - 28; }
        else               { wp = w4; ln = 0;        }
        const float* wrow = wp + (ln * K_ + k) * 16;
        float lg[16];
        float m = -1e30f;
        #pragma unroll
        for (int g = 0; g < 16; ++g) { lg[g] = wrow[g]; m = fmaxf(m, lg[g]); }
        float z = 0.f;
        #pragma unroll
        for (int g = 0; g < 16; ++g) { lg[g] = __expf(lg[g] - m); z += lg[g]; }
        const float inv = 1.0f / z;
        float l0 = 0.f, l1 = 0.f, l2 = 0.f, l3 = 0.f;
        #pragma unroll
        for (int g = 0; g < 16; ++g) {
            float p = lg[g] * inv;           // GATES[g,t] = (g>>t)&1, t = 2*a+b
            if (g & 1) l0 += p;
            if (g & 2) l1 += p;
            if (g & 4) l2 += p;
            if (g & 8) l3 += p;
        }
        s_lut[tid][0] = l0;
        s_lut[tid][1] = l1 - l0;
        s_lut[tid][2] = l2 - l0;
        s_lut[tid][3] = (l3 - l2) - (l1 - l0);
    } else if (tid >= 32 && tid < 64) {
        const int idx  = tid - 32;           // tree*16 + s
        const int tree = idx >> 4;
        const int s    = idx & 15;
        const int off  = ((tree * K_ + k) * S_ + s) * 4;  // kc (2,K,S,4) = (h,w,d,c)
        const int h = kc[off + 0], w = kc[off + 1], d = kc[off + 2], c = kc[off + 3];
        s_lb[idx] = ((c * H_ + h) * W_ + w) * D_ + d;
    }
    __syncthreads();

    // block-uniform leaf bases -> SGPRs
    int sA[16], sB[16];
    #pragma unroll
    for (int s = 0; s < 16; ++s) {
        sA[s] = __builtin_amdgcn_readfirstlane(s_lb[s]);
        sB[s] = __builtin_amdgcn_readfirstlane(s_lb[16 + s]);
    }

    // fold batch + oh into one SGPR base pointer
    const float* xb2 = x + (size_t)b * (C_ * H_ * W_ * D_) + oh * (W_ * D_);

    // ---- 4 positions/thread: p = tid + 256*pi; only pi=3 can be inactive ----
    const int p3   = tid + 768;
    const bool a3  = (p3 < 900);
    const int q3   = a3 ? p3 : 899;
    const int ow0 = tid / 30,        od0 = tid - ow0 * 30;
    const int ow1 = (tid + 256) / 30, od1 = (tid + 256) - ow1 * 30;
    const int ow2 = (tid + 512) / 30, od2 = (tid + 512) - ow2 * 30;
    const int ow3 = q3 / 30,          od3 = q3 - ow3 * 30;
    const int o0 = ow0 * D_ + od0;
    const int o1 = ow1 * D_ + od1;
    const int o2 = ow2 * D_ + od2;
    const int o3 = ow3 * D_ + od3;

    v2f v01[16], v23[16];
    #pragma unroll
    for (int s = 0; s < 16; ++s) {
        const int ba = sA[s], bb = sB[s];
        v2f A01, A23, B01, B23;
        A01.x = xb2[ba + o0]; A01.y = xb2[ba + o1];
        A23.x = xb2[ba + o2]; A23.y = xb2[ba + o3];
        B01.x = xb2[bb + o0]; B01.y = xb2[bb + o1];
        B23.x = xb2[bb + o2]; B23.y = xb2[bb + o3];
        const float l0 = s_lut[s][0], d1 = s_lut[s][1], d2 = s_lut[s][2], d3 = s_lut[s][3];
        v01[s] = lut2(A01, B01, l0, d1, d2, d3);
        v23[s] = lut2(A23, B23, l0, d1, d2, d3);
    }

    #pragma unroll
    for (int lvl = 0; lvl < 4; ++lvl) {
        const int width = 8 >> lvl;              // 8,4,2,1
        const int nbase = (lvl == 0) ? 16 : (lvl == 1) ? 24 : (lvl == 2) ? 28 : 30;
        #pragma unroll
        for (int j = 0; j < width; ++j) {
            const float l0 = s_lut[nbase + j][0], d1 = s_lut[nbase + j][1];
            const float d2 = s_lut[nbase + j][2], d3 = s_lut[nbase + j][3];
            v01[j] = lut2(v01[2 * j], v01[2 * j + 1], l0, d1, d2, d3);
            v23[j] = lut2(v23[2 * j], v23[2 * j + 1], l0, d1, d2, d3);
        }
    }

    float* outp = out + (size_t)bk * 27000 + oh * 900;
    outp[tid]       = v01[0].x;
    outp[tid + 256] = v01[0].y;
    outp[tid + 512] = v23[0].x;
    if (a3) outp[p3] = v23[0].y;
}

extern "C" void kernel_launch(void* const* d_in, const int* in_sizes, int n_in,
                              void* d_out, int out_size, void* d_ws, size_t ws_size,
                              hipStream_t stream) {
    const float* x  = (const float*)d_in[0];
    const int*   kc = (const int*)d_in[1];
    const float* w0 = (const float*)d_in[2];
    const float* w1 = (const float*)d_in[3];
    const float* w2 = (const float*)d_in[4];
    const float* w3 = (const float*)d_in[5];
    const float* w4 = (const float*)d_in[6];
    float* out = (float*)d_out;

    dim3 grid(B_ * K_, 30);  // (bk, oh) = 3840 blocks
    logic_conv3d<<<grid, TPB, 0, stream>>>(x, kc, w0, w1, w2, w3, w4, out);
}

// Round 6
// 87.530 us; speedup vs baseline: 6.5988x; 1.0995x over previous
//
#include <hip/hip_runtime.h>

// LogicConv3d: B=4, C=3, H=W=D=32, K=32, S=16 leaves, tree depth 4 (31 LUT nodes).
// Out: (B, K, 30, 30, 30) = 3,456,000 fp32.
//
// R5: od-blocked gathers. Thread = (ow, g) with 4 CONSECUTIVE od per thread
// (od0 = min(4g,26); g=7 overlaps g=6 by 2 -> duplicate identical stores,
// keeps every quad inside one 128B d-row: no row crossing, no OOB). A leaf
// gather = ONE float4 load (4x fewer VMEM instrs than R4), and a wave spans
// only 8 consecutive ow rows -> leaf pass touches ~12.7KB (L1-resident) vs
// R4's full 37KB window per wave (L1 thrash across 4 resident blocks).
// Loads consumed per-leaf (R3 lesson: hoisting spilled to scratch).

#define B_  4
#define C_  3
#define H_  32
#define W_  32
#define D_  32
#define K_  32
#define S_  16
#define TPB 256

typedef float v4f __attribute__((ext_vector_type(4), aligned(4)));

__device__ __forceinline__ v4f lut4(v4f a, v4f b, float l0, float d1, float d2, float d3) {
    // E = l0 + a*d2 + b*d1 + (a*b)*d3  -> 8 v_pk_fma/pk_mul for 4 positions
    v4f t = a * d2 + l0;
    t = b * d1 + t;
    t = (a * b) * d3 + t;
    return t;
}

__global__ __launch_bounds__(TPB, 4) void logic_conv3d(
    const float* __restrict__ x,
    const int*   __restrict__ kc,
    const float* __restrict__ w0,
    const float* __restrict__ w1,
    const float* __restrict__ w2,
    const float* __restrict__ w3,
    const float* __restrict__ w4,
    float*       __restrict__ out)
{
    __shared__ float4 s_lut[31];     // (l0, d1, d2, d3) per node
    __shared__ int    s_lb[32];      // leaf dword base in flattened (C,H,W,D), oh-independent

    const int bk  = blockIdx.x;      // b*K + k
    const int oh  = blockIdx.y;      // 0..29
    const int b   = bk >> 5;
    const int k   = bk & 31;
    const int tid = threadIdx.x;

    // ---- per-block setup: 31 softmax->LUT (delta form) + 32 leaf bases ----
    if (tid < 31) {
        const float* wp; int ln;
        if      (tid < 16) { wp = w0; ln = tid;      }
        else if (tid < 24) { wp = w1; ln = tid - 16; }
        else if (tid < 28) { wp = w2; ln = tid - 24; }
        else if (tid < 30) { wp = w3; ln = tid - 28; }
        else               { wp = w4; ln = 0;        }
        const float* wrow = wp + (ln * K_ + k) * 16;
        float lg[16];
        float m = -1e30f;
        #pragma unroll
        for (int g = 0; g < 16; ++g) { lg[g] = wrow[g]; m = fmaxf(m, lg[g]); }
        float z = 0.f;
        #pragma unroll
        for (int g = 0; g < 16; ++g) { lg[g] = __expf(lg[g] - m); z += lg[g]; }
        const float inv = 1.0f / z;
        float l0 = 0.f, l1 = 0.f, l2 = 0.f, l3 = 0.f;
        #pragma unroll
        for (int g = 0; g < 16; ++g) {
            float p = lg[g] * inv;           // GATES[g,t] = (g>>t)&1, t = 2*a+b
            if (g & 1) l0 += p;
            if (g & 2) l1 += p;
            if (g & 4) l2 += p;
            if (g & 8) l3 += p;
        }
        s_lut[tid] = make_float4(l0, l1 - l0, l2 - l0, (l3 - l2) - (l1 - l0));
    } else if (tid >= 32 && tid < 64) {
        const int idx  = tid - 32;           // tree*16 + s
        const int tree = idx >> 4;
        const int s    = idx & 15;
        const int off  = ((tree * K_ + k) * S_ + s) * 4;  // kc (2,K,S,4) = (h,w,d,c)
        const int h = kc[off + 0], w = kc[off + 1], d = kc[off + 2], c = kc[off + 3];
        s_lb[idx] = ((c * H_ + h) * W_ + w) * D_ + d;
    }
    __syncthreads();

    // block-uniform leaf bases -> SGPRs
    int sA[16], sB[16];
    #pragma unroll
    for (int s = 0; s < 16; ++s) {
        sA[s] = __builtin_amdgcn_readfirstlane(s_lb[s]);
        sB[s] = __builtin_amdgcn_readfirstlane(s_lb[16 + s]);
    }

    // fold batch + oh into one base pointer
    const float* xb2 = x + (size_t)b * (C_ * H_ * W_ * D_) + oh * (W_ * D_);

    // thread -> (ow, quad of consecutive od)
    const int g   = tid & 7;
    int ow        = tid >> 3;
    if (ow > 29) ow = 29;                    // tid>=240: duplicate ow=29 work (no OOB, no divergence)
    const int od0 = (g < 7) ? (g << 2) : 26; // quad start; g=7 overlaps g=6 by 2 (identical values)
    const int vo  = ow * D_ + od0;           // per-thread dword offset within window

    v4f v[16];
    #pragma unroll
    for (int s = 0; s < 16; ++s) {
        const v4f A = *(const v4f*)(xb2 + sA[s] + vo);
        const v4f Bv = *(const v4f*)(xb2 + sB[s] + vo);
        const float4 L = s_lut[s];
        v[s] = lut4(A, Bv, L.x, L.y, L.z, L.w);
    }

    #pragma unroll
    for (int lvl = 0; lvl < 4; ++lvl) {
        const int width = 8 >> lvl;              // 8,4,2,1
        const int nbase = (lvl == 0) ? 16 : (lvl == 1) ? 24 : (lvl == 2) ? 28 : 30;
        #pragma unroll
        for (int j = 0; j < width; ++j) {
            const float4 L = s_lut[nbase + j];
            v[j] = lut4(v[2 * j], v[2 * j + 1], L.x, L.y, L.z, L.w);
        }
    }

    // store 4 consecutive od (overlaps/duplicates write identical values)
    float* outp = out + (size_t)bk * 27000 + oh * 900 + ow * 30 + od0;
    *(v4f*)outp = v[0];
}

extern "C" void kernel_launch(void* const* d_in, const int* in_sizes, int n_in,
                              void* d_out, int out_size, void* d_ws, size_t ws_size,
                              hipStream_t stream) {
    const float* x  = (const float*)d_in[0];
    const int*   kc = (const int*)d_in[1];
    const float* w0 = (const float*)d_in[2];
    const float* w1 = (const float*)d_in[3];
    const float* w2 = (const float*)d_in[4];
    const float* w3 = (const float*)d_in[5];
    const float* w4 = (const float*)d_in[6];
    float* out = (float*)d_out;

    dim3 grid(B_ * K_, 30);  // (bk, oh) = 3840 blocks
    logic_conv3d<<<grid, TPB, 0, stream>>>(x, kc, w0, w1, w2, w3, w4, out);
}